// Round 6
// baseline (17785.991 us; speedup 1.0000x reference)
//
#include <hip/hip_runtime.h>
#include <cfloat>

#define NRW 32768
#define KC 4096
#define CD 256
#define HW 1024

// exact numpy fp32 MAC: mul and add separately rounded (contract off in kernel)
#define MAC4(accv, xv, ev) do { \
  float p0 = (xv).x * (ev).x; (accv).x = (accv).x + p0; \
  float p1 = (xv).y * (ev).y; (accv).y = (accv).y + p1; \
  float p2 = (xv).z * (ev).z; (accv).z = (accv).z + p2; \
  float p3 = (xv).w * (ev).w; (accv).w = (accv).w + p3; } while (0)

// ---------- se[k] = np.sum(cb[k]**2) : numpy pairwise (128+128, scalar 8-acc) ----------
__global__ __launch_bounds__(256) void vq_se(const float* __restrict__ cb,
                                             float* __restrict__ se) {
#pragma clang fp contract(off)
  const int tid = threadIdx.x;
  const int g = tid >> 3;
  const int j = tid & 7;
  const int code = blockIdx.x * 32 + g;
  const float* e = cb + (size_t)code * CD;
  float half[2];
#pragma unroll
  for (int h = 0; h < 2; ++h) {
    const float* a = e + h * 128;
    float v = a[j];
    float r = v * v;
#pragma unroll
    for (int i = 1; i < 16; ++i) {
      float w = a[8 * i + j];
      float w2 = w * w;
      r = r + w2;
    }
    float l1 = r + __shfl_down(r, 1, 8);
    float l2 = l1 + __shfl_down(l1, 2, 8);
    float l3 = l2 + __shfl_down(l2, 4, 8);
    half[h] = l3;
  }
  if (j == 0) se[code] = half[0] + half[1];
}

// swizzled x LDS address: row r, channel c -> depth-8 optimal column reads
__device__ __forceinline__ int xaddr(int r, int c) {
  return r * 256 + ((((c >> 2) ^ (r & 7)) << 2) | (c & 3));
}

// ---------- main: 32 rows/block, 8 code-groups of 512, batched e-loads ----------
__global__ __launch_bounds__(256, 4) void vq_dist(const float* __restrict__ x,
                                                  const float* __restrict__ cb,
                                                  const float* __restrict__ se,
                                                  float* __restrict__ outids) {
#pragma clang fp contract(off)
  __shared__ float xs[32 * 256];    // 32 KB; reused for the final merge

  const int tid = threadIdx.x;
  const int l   = tid & 63;
  const int r   = tid & 31;         // row (2 lanes per row)
  const int g   = tid >> 5;         // code group 0..7 -> codes [512g, 512g+512)
  const int b   = blockIdx.x >> 5;
  const int hw0 = (blockIdx.x & 31) << 5;
  const float* xb = x + (size_t)b * CD * HW + hw0;

  // ---- stage x: thread = channel, 8 float4 over 32 rows ----
  {
    const float* src = xb + (size_t)tid * HW;
#pragma unroll
    for (int f = 0; f < 8; ++f) {
      const float4 v = *(const float4*)(src + 4 * f);
      xs[xaddr(4 * f + 0, tid)] = v.x;
      xs[xaddr(4 * f + 1, tid)] = v.y;
      xs[xaddr(4 * f + 2, tid)] = v.z;
      xs[xaddr(4 * f + 3, tid)] = v.w;
    }
  }
  __syncthreads();

  // ---- sx for own row: numpy pairwise (128+128, scalar 8-acc), serial per lane ----
  float sx;
  {
    float half[2];
#pragma unroll
    for (int h = 0; h < 2; ++h) {
      float racc[8];
#pragma unroll
      for (int j = 0; j < 8; ++j) {
        const float v = xs[xaddr(r, h * 128 + j)];
        racc[j] = v * v;
      }
#pragma unroll
      for (int i = 1; i < 16; ++i) {
#pragma unroll
        for (int j = 0; j < 8; ++j) {
          const float v = xs[xaddr(r, h * 128 + 8 * i + j)];
          const float v2 = v * v;
          racc[j] = racc[j] + v2;
        }
      }
      half[h] = ((racc[0] + racc[1]) + (racc[2] + racc[3])) +
                ((racc[4] + racc[5]) + (racc[6] + racc[7]));
    }
    sx = half[0] + half[1];
  }

  const int kbase = g << 9;               // this thread's 512-code range
  const float* xrow = xs + r * 256;
  const int s = r & 7;

  float m1 = FLT_MAX;
  int   mi = 0;

#pragma unroll 1
  for (int kt = 0; kt < 64; ++kt) {
    float4 acc[8];
#pragma unroll
    for (int t = 0; t < 8; ++t) { acc[t].x = 0.f; acc[t].y = 0.f; acc[t].z = 0.f; acc[t].w = 0.f; }
    const float* e0 = cb + (size_t)(kbase + kt * 8) * CD;

#pragma unroll
    for (int cc = 0; cc < 8; ++cc) {
      float4 xf[8];
#pragma unroll
      for (int f = 0; f < 8; ++f)
        xf[f] = *(const float4*)(xrow + ((cc * 8 + (f ^ s)) << 2));
#pragma unroll
      for (int t = 0; t < 8; ++t) {
        const float* ept = e0 + t * CD + cc * 32;
        // batch all 8 e-loads, then MAC in exact numpy order (B asc, j=3..0)
        const float4 e3 = *(const float4*)(ept + 12);
        const float4 e2 = *(const float4*)(ept + 8);
        const float4 e1 = *(const float4*)(ept + 4);
        const float4 e0v = *(const float4*)(ept + 0);
        const float4 e7 = *(const float4*)(ept + 28);
        const float4 e6 = *(const float4*)(ept + 24);
        const float4 e5 = *(const float4*)(ept + 20);
        const float4 e4 = *(const float4*)(ept + 16);
        MAC4(acc[t], xf[3], e3);
        MAC4(acc[t], xf[2], e2);
        MAC4(acc[t], xf[1], e1);
        MAC4(acc[t], xf[0], e0v);
        MAC4(acc[t], xf[7], e7);
        MAC4(acc[t], xf[6], e6);
        MAC4(acc[t], xf[5], e5);
        MAC4(acc[t], xf[4], e4);
      }
    }

    // finish 8 dots: SSE tree, sq = se+sx, dist = sq - 2*dot; first-min (k ascends)
#pragma unroll
    for (int t = 0; t < 8; ++t) {
      const float dot  = (acc[t].x + acc[t].y) + (acc[t].z + acc[t].w);
      const float sq   = se[kbase + kt * 8 + t] + sx;
      const float td   = 2.0f * dot;
      const float dist = sq - td;
      const int k = kbase + kt * 8 + t;
      if (dist < m1) { m1 = dist; mi = k; }
    }
  }

  // ---- merge 8 code-groups per row (xs is dead; overlay) ----
  __syncthreads();
  float* ms  = xs;                 // [8][32]
  int*   mis = (int*)(xs + 256);   // [8][32]
  ms[tid]  = m1;
  mis[tid] = mi;
  __syncthreads();
  if (tid < 32) {
    float best = ms[tid];
    int   bi   = mis[tid];
#pragma unroll
    for (int gg = 1; gg < 8; ++gg) {
      const float v  = ms[gg * 32 + tid];
      const int   ix = mis[gg * 32 + tid];
      if (v < best || (v == best && ix < bi)) { best = v; bi = ix; }
    }
    outids[b * HW + hw0 + tid] = (float)bi;
  }
}

// ---------- emb gather ----------
__global__ __launch_bounds__(256) void vq_emb_out(const float* __restrict__ outids,
                                                  const float* __restrict__ cb,
                                                  float* __restrict__ out) {
  const int bx = blockIdx.x;
  const int b = bx >> 10;
  const int rem = bx & 1023;
  const int c = rem >> 2;
  const int q = rem & 3;
  const int hw = q * 256 + threadIdx.x;
  const int id = (int)outids[b * HW + hw];
  out[((size_t)(b * CD + c)) * HW + hw] = cb[(size_t)id * CD + c];
}

extern "C" void kernel_launch(void* const* d_in, const int* in_sizes, int n_in,
                              void* d_out, int out_size, void* d_ws, size_t ws_size,
                              hipStream_t stream) {
  const float* x  = (const float*)d_in[0];   // (32,256,32,32) f32
  const float* cb = (const float*)d_in[1];   // (4096,256) f32
  float* out = (float*)d_out;                // [0..32767]=ids, [32768..]=emb (B,C,H,W)

  float* se = (float*)d_ws;                  // 16 KB

  vq_se<<<128, 256, 0, stream>>>(cb, se);
  vq_dist<<<1024, 256, 0, stream>>>(x, cb, se, out);
  vq_emb_out<<<32768, 256, 0, stream>>>(out, cb, out + NRW);
}

// Round 7
// 1495.454 us; speedup vs baseline: 11.8934x; 11.8934x over previous
//
#include <hip/hip_runtime.h>
#include <cfloat>

#define NRW 32768
#define KC 4096
#define CD 256
#define HW 1024

// scalar x times float4-of-codes e, numpy rounding (mul & add separately rounded)
#define MACS(accv, xsc, ev) do { \
  float p0 = (xsc) * (ev).x; (accv).x = (accv).x + p0; \
  float p1 = (xsc) * (ev).y; (accv).y = (accv).y + p1; \
  float p2 = (xsc) * (ev).z; (accv).z = (accv).z + p2; \
  float p3 = (xsc) * (ev).w; (accv).w = (accv).w + p3; } while (0)

// ---------- se[k] = np.sum(cb[k]**2) : numpy pairwise (128+128, scalar 8-acc) ----------
__global__ __launch_bounds__(256) void vq_se(const float* __restrict__ cb,
                                             float* __restrict__ se) {
#pragma clang fp contract(off)
  const int tid = threadIdx.x;
  const int g = tid >> 3;
  const int j = tid & 7;
  const int code = blockIdx.x * 32 + g;
  const float* e = cb + (size_t)code * CD;
  float half[2];
#pragma unroll
  for (int h = 0; h < 2; ++h) {
    const float* a = e + h * 128;
    float v = a[j];
    float r = v * v;
#pragma unroll
    for (int i = 1; i < 16; ++i) {
      float w = a[8 * i + j];
      float w2 = w * w;
      r = r + w2;
    }
    float l1 = r + __shfl_down(r, 1, 8);
    float l2 = l1 + __shfl_down(l1, 2, 8);
    float l3 = l2 + __shfl_down(l2, 4, 8);
    half[h] = l3;
  }
  if (j == 0) se[code] = half[0] + half[1];
}

// swizzled x LDS address: [row][ch], granule XOR keeps all reads/writes <=2-way
__device__ __forceinline__ int xaddr(int row, int ch) {
  const int g = (ch >> 2) ^ (row & 3) ^ (((row >> 2) & 1) << 2);
  return row * 256 + (g << 2) + (ch & 3);
}

// ---------- main: x resident in LDS, e triple-buffered LDS chunks, 4x4 micro-tile ----------
__global__ __launch_bounds__(256, 2) void vq_dist(const float* __restrict__ x,
                                                  const float* __restrict__ cb,
                                                  const float* __restrict__ se,
                                                  float* __restrict__ outids) {
#pragma clang fp contract(off)
  __shared__ float xs[64 * 256];     // 64 KB  swizzled [row][ch]
  __shared__ float es[3 * 16 * 64];  // 12 KB  triple-buffered e-chunk [ch16][code64]
  __shared__ float sxs[64];

  const int tid = threadIdx.x;
  const int tx  = tid & 15;          // code quad -> codes bn*64 + 4tx..+3
  const int ty  = tid >> 4;          // row quad  -> rows 4ty..4ty+3
  const int b   = blockIdx.x >> 4;
  const int hw0 = (blockIdx.x & 15) << 6;
  const float* xb = x + (size_t)b * CD * HW + hw0;

  // ---- stage x once: thread = channel, float4 over rows, swizzled scalar writes ----
  {
    const float* src = xb + (size_t)tid * HW;
#pragma unroll
    for (int f = 0; f < 16; ++f) {
      const float4 v = *(const float4*)(src + 4 * f);
      xs[xaddr(4 * f + 0, tid)] = v.x;
      xs[xaddr(4 * f + 1, tid)] = v.y;
      xs[xaddr(4 * f + 2, tid)] = v.z;
      xs[xaddr(4 * f + 3, tid)] = v.w;
    }
  }
  __syncthreads();

  // ---- sx per row: numpy pairwise (128+128, scalar 8-acc), serial per thread ----
  if (tid < 64) {
    const int row = tid;
    float half[2];
#pragma unroll
    for (int h = 0; h < 2; ++h) {
      float racc[8];
#pragma unroll
      for (int j = 0; j < 8; ++j) {
        const float v = xs[xaddr(row, h * 128 + j)];
        racc[j] = v * v;
      }
#pragma unroll
      for (int i = 1; i < 16; ++i) {
#pragma unroll
        for (int j = 0; j < 8; ++j) {
          const float v = xs[xaddr(row, h * 128 + 8 * i + j)];
          const float v2 = v * v;
          racc[j] = racc[j] + v2;
        }
      }
      half[h] = ((racc[0] + racc[1]) + (racc[2] + racc[3])) +
                ((racc[4] + racc[5]) + (racc[6] + racc[7]));
    }
    sxs[row] = half[0] + half[1];
  }

  // ---- e-stream prologue: chunk q = bn*16+bk; thread loads code=tid&63, chquad=tid>>6 ----
  const int ecl = tid & 63;
  const int ecq = tid >> 6;
  float4 v = *(const float4*)(cb + (size_t)ecl * CD + 4 * ecq);          // q=0
  {
    float* d = es + (4 * ecq) * 64 + ecl;
    d[0] = v.x; d[64] = v.y; d[128] = v.z; d[192] = v.w;
  }
  float4 vn = *(const float4*)(cb + (size_t)ecl * CD + 16 + 4 * ecq);    // q=1
  __syncthreads();

  float sxr[4];
#pragma unroll
  for (int r = 0; r < 4; ++r) sxr[r] = sxs[4 * ty + r];

  float4 acc[4][4];                  // [row r][sse l], float4 over 4 codes
#pragma unroll
  for (int r = 0; r < 4; ++r)
#pragma unroll
    for (int l = 0; l < 4; ++l) { acc[r][l].x = 0.f; acc[r][l].y = 0.f; acc[r][l].z = 0.f; acc[r][l].w = 0.f; }

  float m1[4];
  int   mi[4];
#pragma unroll
  for (int r = 0; r < 4; ++r) { m1[r] = FLT_MAX; mi[r] = 0; }

  int cur = 0, q = 0;
#pragma unroll 1
  for (int bn = 0; bn < 64; ++bn) {
    const float4 se4 = *(const float4*)(se + bn * 64 + 4 * tx);
#pragma unroll 1
    for (int bk = 0; bk < 16; ++bk, ++q) {
      int nxt = cur + 1; if (nxt == 3) nxt = 0;
      if (q < 1023) {                          // publish chunk q+1
        float* d = es + nxt * 1024 + (4 * ecq) * 64 + ecl;
        d[0] = vn.x; d[64] = vn.y; d[128] = vn.z; d[192] = vn.w;
      }
      if (q < 1022) {                          // prefetch chunk q+2 into regs
        const int q2 = q + 2;
        vn = *(const float4*)(cb + (size_t)((q2 >> 4) * 64 + ecl) * CD + (q2 & 15) * 16 + 4 * ecq);
      }
      // compute chunk q from es[cur]: numpy order (block=chunk asc, j=3..0)
      const float* eb = es + cur * 1024;
#pragma unroll
      for (int j = 3; j >= 0; --j) {
        float4 xv[4], ev[4];
#pragma unroll
        for (int r = 0; r < 4; ++r) {
          const int row = 4 * ty + r;
          const int g = (4 * bk + j) ^ r ^ ((ty & 1) << 2);
          xv[r] = *(const float4*)(xs + row * 256 + (g << 2));
        }
#pragma unroll
        for (int l = 0; l < 4; ++l)
          ev[l] = *(const float4*)(eb + (4 * j + l) * 64 + 4 * tx);
#pragma unroll
        for (int r = 0; r < 4; ++r) {
          MACS(acc[r][0], xv[r].x, ev[0]);
          MACS(acc[r][1], xv[r].y, ev[1]);
          MACS(acc[r][2], xv[r].z, ev[2]);
          MACS(acc[r][3], xv[r].w, ev[3]);
        }
      }
      __syncthreads();
      cur = nxt;
    }
    // epilogue: SSE tree, sq = se+sx, dist = sq - 2*dot, running first-min
#pragma unroll
    for (int r = 0; r < 4; ++r) {
      float4 dotv;
      dotv.x = (acc[r][0].x + acc[r][1].x) + (acc[r][2].x + acc[r][3].x);
      dotv.y = (acc[r][0].y + acc[r][1].y) + (acc[r][2].y + acc[r][3].y);
      dotv.z = (acc[r][0].z + acc[r][1].z) + (acc[r][2].z + acc[r][3].z);
      dotv.w = (acc[r][0].w + acc[r][1].w) + (acc[r][2].w + acc[r][3].w);
      const float d0 = (se4.x + sxr[r]) - 2.0f * dotv.x;
      const float d1 = (se4.y + sxr[r]) - 2.0f * dotv.y;
      const float d2 = (se4.z + sxr[r]) - 2.0f * dotv.z;
      const float d3 = (se4.w + sxr[r]) - 2.0f * dotv.w;
      const int kb = bn * 64 + 4 * tx;
      if (d0 < m1[r]) { m1[r] = d0; mi[r] = kb; }
      if (d1 < m1[r]) { m1[r] = d1; mi[r] = kb + 1; }
      if (d2 < m1[r]) { m1[r] = d2; mi[r] = kb + 2; }
      if (d3 < m1[r]) { m1[r] = d3; mi[r] = kb + 3; }
#pragma unroll
      for (int l = 0; l < 4; ++l) { acc[r][l].x = 0.f; acc[r][l].y = 0.f; acc[r][l].z = 0.f; acc[r][l].w = 0.f; }
    }
  }

  // ---- merge per row across 16 tx (codes ascend with tx -> first-index) ----
  float* ms  = es;                  // [64][16]
  int*   mis = (int*)(es + 1024);   // [64][16]
#pragma unroll
  for (int r = 0; r < 4; ++r) {
    ms[(4 * ty + r) * 16 + tx]  = m1[r];
    mis[(4 * ty + r) * 16 + tx] = mi[r];
  }
  __syncthreads();
  if (tid < 64) {
    float best = ms[tid * 16];
    int   bi   = mis[tid * 16];
#pragma unroll
    for (int t = 1; t < 16; ++t) {
      const float vv = ms[tid * 16 + t];
      const int   ix = mis[tid * 16 + t];
      if (vv < best || (vv == best && ix < bi)) { best = vv; bi = ix; }
    }
    outids[b * HW + hw0 + tid] = (float)bi;
  }
}

// ---------- emb gather ----------
__global__ __launch_bounds__(256) void vq_emb_out(const float* __restrict__ outids,
                                                  const float* __restrict__ cb,
                                                  float* __restrict__ out) {
  const int bx = blockIdx.x;
  const int b = bx >> 10;
  const int rem = bx & 1023;
  const int c = rem >> 2;
  const int q = rem & 3;
  const int hw = q * 256 + threadIdx.x;
  const int id = (int)outids[b * HW + hw];
  out[((size_t)(b * CD + c)) * HW + hw] = cb[(size_t)id * CD + c];
}

extern "C" void kernel_launch(void* const* d_in, const int* in_sizes, int n_in,
                              void* d_out, int out_size, void* d_ws, size_t ws_size,
                              hipStream_t stream) {
  const float* x  = (const float*)d_in[0];   // (32,256,32,32) f32
  const float* cb = (const float*)d_in[1];   // (4096,256) f32
  float* out = (float*)d_out;                // [0..32767]=ids, [32768..]=emb (B,C,H,W)

  float* se = (float*)d_ws;                  // 16 KB

  vq_se<<<128, 256, 0, stream>>>(cb, se);
  vq_dist<<<512, 256, 0, stream>>>(x, cb, se, out);
  vq_emb_out<<<32768, 256, 0, stream>>>(out, cb, out + NRW);
}